// Round 4
// baseline (323.657 us; speedup 1.0000x reference)
//
#include <hip/hip_runtime.h>
#include <hip/hip_bf16.h>

typedef unsigned short u16;
typedef unsigned long long u64;
typedef __bf16 bf16x8 __attribute__((ext_vector_type(8)));
typedef float f32x4 __attribute__((ext_vector_type(4)));

#define S_DIM 2048
#define B_DIM 32
#define H_DIM 1024
#define M_DIM (S_DIM * B_DIM)
#define BM 64
#define BKS 32
#define NKS (H_DIM / BKS)

__device__ __forceinline__ float fast_tanh(float x) {
  // tanh(x) = 1 - 2/(e^{2x}+1); e->inf => 1, e->0 => -1; no NaN
  float e = __expf(2.0f * x);
  return 1.0f - 2.0f * __builtin_amdgcn_rcpf(e + 1.0f);
}

// Convert W_attn[:, H:2H] (f32, row stride 2H) -> W2 bf16 [H][H] row-major
__global__ void wconv_kernel(const float* __restrict__ W, u16* __restrict__ W2) {
  const int h = blockIdx.x;
  const int t = threadIdx.x; // 256 threads, 4 floats each
  float4 w4 = *(const float4*)(W + (size_t)h * (2 * H_DIM) + H_DIM + t * 4);
  union { u16 s[4]; uint2 v; } pk;
  pk.s[0] = __builtin_bit_cast(u16, (__bf16)w4.x);
  pk.s[1] = __builtin_bit_cast(u16, (__bf16)w4.y);
  pk.s[2] = __builtin_bit_cast(u16, (__bf16)w4.z);
  pk.s[3] = __builtin_bit_cast(u16, (__bf16)w4.w);
  *(uint2*)(W2 + (size_t)h * H_DIM + t * 4) = pk.v;
}

// u[b][h] = dot(hidden[b,:], W_attn[h, 0:H]) + b_attn[h]   (fp32)
__global__ void uprep_kernel(const float* __restrict__ hidden, const float* __restrict__ W,
                             const float* __restrict__ bias, float* __restrict__ u) {
  int t = blockIdx.x * 256 + threadIdx.x;   // 0..131071
  int h = t >> 7;
  int b = (t >> 2) & 31;
  int kq = t & 3;
  const float4* hv = (const float4*)(hidden + (size_t)b * H_DIM) + kq * 64;
  const float4* wv = (const float4*)(W + (size_t)h * (2 * H_DIM)) + kq * 64;
  float acc = 0.f;
  #pragma unroll 4
  for (int i = 0; i < 64; ++i) {
    float4 a = hv[i], w = wv[i];
    acc += a.x * w.x + a.y * w.y + a.z * w.z + a.w * w.w;
  }
  acc += __shfl_xor(acc, 1);
  acc += __shfl_xor(acc, 2);
  if (kq == 0) u[(size_t)b * H_DIM + h] = acc + bias[h];
}

// Fused GEMM + tanh + v-dot.
// Block: BM=64 rows x full N=1024. 512 threads = 8 waves; wave tile 64m x 128n.
// B (W2 bf16) read DIRECTLY from L2 into register fragments (perfectly coalesced:
// 16 rows x 64B fully-used lines per instruction), prefetched one ks ahead.
// No B LDS -> no vmcnt(0) barrier drain on the B path. A (enc f32->bf16)
// reg-staged into small padded LDS, double-buffered. acc[4][8]=128 f32/thread.
__launch_bounds__(512, 2)
__global__ void gemm_kernel(const float* __restrict__ enc, const u16* __restrict__ W2,
                            const float* __restrict__ u, const float* __restrict__ v,
                            float* __restrict__ scores) {
  __shared__ u16 A_s[2][BM][40];        // 80B rows -> 2-way banks (free)
  __shared__ float red_s[8][BM];

  const int tid  = threadIdx.x;
  const int lane = tid & 63;
  const int wid  = tid >> 6;    // 0..7
  const int q    = lane >> 4;   // 0..3 (k-chunk)
  const int c16  = lane & 15;
  const int n0   = wid * 128;   // wave n-slice (128 cols)
  const int m0   = blockIdx.x * BM;

  // A staging coords: thread -> (row 0..63, 4-float chunk 0..7)
  const int ar  = tid >> 3;
  const int acf = tid & 7;
  const float* aptr = enc + (size_t)(m0 + ar) * H_DIM + acf * 4;

  // per-lane B base: row (n0 + c16), k-chunk q
  const u16* wbase = W2 + (size_t)(n0 + c16) * H_DIM + q * 8;

  f32x4 acc[4][8];
  #pragma unroll
  for (int mi = 0; mi < 4; ++mi)
    #pragma unroll
    for (int nf = 0; nf < 8; ++nf) {
      f32x4 z = {0.f, 0.f, 0.f, 0.f};
      acc[mi][nf] = z;
    }

  #define LOADB(dst, ks)                                                       \
    {                                                                          \
      _Pragma("unroll")                                                        \
      for (int nf = 0; nf < 8; ++nf)                                           \
        dst[nf] = *(const bf16x8*)(wbase + (size_t)nf * 16 * H_DIM + (ks) * BKS); \
    }

  #define WRITE_A(buf, f4)                                                     \
    {                                                                          \
      union { u16 s[4]; u64 v; } pk;                                           \
      pk.s[0] = __builtin_bit_cast(u16, (__bf16)(f4).x);                       \
      pk.s[1] = __builtin_bit_cast(u16, (__bf16)(f4).y);                       \
      pk.s[2] = __builtin_bit_cast(u16, (__bf16)(f4).z);                       \
      pk.s[3] = __builtin_bit_cast(u16, (__bf16)(f4).w);                       \
      *(u64*)&A_s[buf][ar][acf * 4] = pk.v;                                    \
    }

  // One k-step. BUFC = A LDS buffer parity; BCUR = current B regs; BNXT = next.
  #define KSTEP(ks, BUFC, BCUR, BNXT)                                          \
    {                                                                          \
      float4 av;                                                               \
      const bool pf = (ks) + 1 < NKS;                                          \
      if (pf) {                                                                \
        LOADB(BNXT, (ks) + 1);                                                 \
        av = *(const float4*)(aptr + ((ks) + 1) * BKS);                        \
      }                                                                        \
      bf16x8 a[4];                                                             \
      _Pragma("unroll")                                                        \
      for (int mi = 0; mi < 4; ++mi)                                           \
        a[mi] = *(const bf16x8*)&A_s[BUFC][mi * 16 + c16][q * 8];              \
      _Pragma("unroll")                                                        \
      for (int nf = 0; nf < 8; ++nf)                                           \
        _Pragma("unroll")                                                      \
        for (int mi = 0; mi < 4; ++mi)                                         \
          acc[mi][nf] = __builtin_amdgcn_mfma_f32_16x16x32_bf16(               \
              a[mi], BCUR[nf], acc[mi][nf], 0, 0, 0);                          \
      if (pf) WRITE_A((BUFC) ^ 1, av);                                         \
      __syncthreads();                                                         \
    }

  // ---- prologue ----
  bf16x8 breg0[8], breg1[8];
  LOADB(breg0, 0);
  {
    float4 a0 = *(const float4*)(aptr);
    WRITE_A(0, a0);
  }
  __syncthreads();

  // ---- K loop: 2 k-steps per iteration (static B reg sets, static A parity) ----
  for (int ks2 = 0; ks2 < NKS / 2; ++ks2) {
    const int ks = ks2 * 2;
    KSTEP(ks, 0, breg0, breg1);
    KSTEP(ks + 1, 1, breg1, breg0);
  }

  // ---- epilogue: rowsum += v[h] * tanh(acc + u[b][h]), reduce over h ----
  float rowsum[4][4];
  #pragma unroll
  for (int mi = 0; mi < 4; ++mi)
    #pragma unroll
    for (int r = 0; r < 4; ++r) rowsum[mi][r] = 0.f;

  #pragma unroll
  for (int nf = 0; nf < 8; ++nf) {
    const int h = n0 + nf * 16 + c16;
    const float vh = v[h];
    float uv[2][4];
    #pragma unroll
    for (int p = 0; p < 2; ++p)
      #pragma unroll
      for (int r = 0; r < 4; ++r)
        uv[p][r] = u[(size_t)(p * 16 + q * 4 + r) * H_DIM + h]; // b=row&31, row=(mi&1)*16+q*4+r
    #pragma unroll
    for (int mi = 0; mi < 4; ++mi)
      #pragma unroll
      for (int r = 0; r < 4; ++r) {
        float x = acc[mi][nf][r] + uv[mi & 1][r];
        rowsum[mi][r] += vh * fast_tanh(x);
      }
  }
  #pragma unroll
  for (int mi = 0; mi < 4; ++mi)
    #pragma unroll
    for (int r = 0; r < 4; ++r) {
      float s = rowsum[mi][r];
      s += __shfl_xor(s, 1);
      s += __shfl_xor(s, 2);
      s += __shfl_xor(s, 4);
      s += __shfl_xor(s, 8);
      if (c16 == 0) red_s[wid][mi * 16 + q * 4 + r] = s;
    }
  __syncthreads();
  if (tid < BM) {
    float s = 0.f;
    #pragma unroll
    for (int w = 0; w < 8; ++w) s += red_s[w][tid];
    scores[m0 + tid] = s;
  }
  #undef LOADB
  #undef WRITE_A
  #undef KSTEP
}

// softmax over S per batch row b; scores[m] with m = s*B + b; out[b][0][s]
__global__ void softmax_kernel(const float* __restrict__ scores, float* __restrict__ out) {
  const int b = blockIdx.x;
  const int t = threadIdx.x;        // 256
  const int lane = t & 63, wid = t >> 6;
  __shared__ float redm[4], reds[4];
  float loc[8];
  float mx = -3.0e38f;
  #pragma unroll
  for (int i = 0; i < 8; ++i) {
    loc[i] = scores[(size_t)(i * 256 + t) * B_DIM + b];
    mx = fmaxf(mx, loc[i]);
  }
  #pragma unroll
  for (int off = 1; off < 64; off <<= 1) mx = fmaxf(mx, __shfl_xor(mx, off));
  if (lane == 0) redm[wid] = mx;
  __syncthreads();
  mx = fmaxf(fmaxf(redm[0], redm[1]), fmaxf(redm[2], redm[3]));
  float sum = 0.f;
  #pragma unroll
  for (int i = 0; i < 8; ++i) { loc[i] = __expf(loc[i] - mx); sum += loc[i]; }
  #pragma unroll
  for (int off = 1; off < 64; off <<= 1) sum += __shfl_xor(sum, off);
  if (lane == 0) reds[wid] = sum;
  __syncthreads();
  sum = reds[0] + reds[1] + reds[2] + reds[3];
  float inv = 1.0f / sum;
  #pragma unroll
  for (int i = 0; i < 8; ++i) out[(size_t)b * S_DIM + i * 256 + t] = loc[i] * inv;
}

extern "C" void kernel_launch(void* const* d_in, const int* in_sizes, int n_in,
                              void* d_out, int out_size, void* d_ws, size_t ws_size,
                              hipStream_t stream) {
  const float* hidden = (const float*)d_in[0];
  const float* enc    = (const float*)d_in[1];
  const float* W      = (const float*)d_in[2];
  const float* bias   = (const float*)d_in[3];
  const float* v      = (const float*)d_in[4];
  float* out = (float*)d_out;

  char* ws = (char*)d_ws;
  u16*   W2     = (u16*)ws;                                        // 2 MB
  float* u      = (float*)(ws + (2u << 20));                       // 128 KB
  float* scores = (float*)(ws + (2u << 20) + (128u << 10));        // 256 KB

  wconv_kernel<<<H_DIM, 256, 0, stream>>>(W, W2);
  uprep_kernel<<<512, 256, 0, stream>>>(hidden, W, bias, u);
  gemm_kernel<<<M_DIM / BM, 512, 0, stream>>>(enc, W2, u, v, scores);
  softmax_kernel<<<B_DIM, 256, 0, stream>>>(scores, out);
}